// Round 14
// baseline (166.655 us; speedup 1.0000x reference)
//
#include <hip/hip_runtime.h>
#include <hip/hip_bf16.h>

#define NH    8
#define DH    64
#define DIMD  512
#define NCTX  2048
#define NB    4
#define NROWS (NB * NCTX)   // 8192
#define QKVN  (3 * DIMD)    // 1536

typedef __attribute__((ext_vector_type(8))) short bf16x8;
typedef __attribute__((ext_vector_type(4))) float f32x4;

#define INV_LN2 1.44269504f
#define SCLOG   (0.125f * INV_LN2)   // folded into Q at mgemm1 epilogue

__device__ __forceinline__ unsigned short f2bits(float f) {
  unsigned u = __float_as_uint(f);
  u += 0x7fffu + ((u >> 16) & 1u);      // round-to-nearest-even
  return (unsigned short)(u >> 16);
}
__device__ __forceinline__ float bits2f(unsigned short u) {
  return __uint_as_float(((unsigned)u) << 16);
}
// packed bf16 pair via compiled cvt_pk (RTNE; hazard-safe consumer of v_exp)
__device__ __forceinline__ unsigned pk2(float lo, float hi) {
  __hip_bfloat162 h = __float22bfloat162_rn(float2{lo, hi});
  union { __hip_bfloat162 h; unsigned u; } c; c.h = h; return c.u;
}

// ---- global_load_lds wrappers (width 16 / 4). LDS base must be wave-uniform;
// ---- global src is per-lane (pre-swizzled source = swizzled LDS, rule #21).
__device__ __forceinline__ void gll16(const void* g, void* l) {
  __builtin_amdgcn_global_load_lds(
      (const __attribute__((address_space(1))) unsigned int*)g,
      (__attribute__((address_space(3))) unsigned int*)l, 16, 0, 0);
}
__device__ __forceinline__ void gll4(const void* g, void* l) {
  __builtin_amdgcn_global_load_lds(
      (const __attribute__((address_space(1))) unsigned int*)g,
      (__attribute__((address_space(3))) unsigned int*)l, 4, 0, 0);
}

// -------- Merged LayerNorm + weight-transpose + pose-bias prep (one launch) --
// blocks [0,2048): LN rows; [2048,2432): tconv tiles; [2432,2436): pbl.
__global__ __launch_bounds__(256) void lntc_kernel(
    const float* __restrict__ x,
    const float* __restrict__ gamma,
    const float* __restrict__ beta,
    unsigned short* __restrict__ xn,
    const float* __restrict__ in0, unsigned short* __restrict__ out0,
    const float* __restrict__ in1, unsigned short* __restrict__ out1,
    const float* __restrict__ pb, const float* __restrict__ betap,
    float* __restrict__ pbl) {
  __shared__ float T[64][65];
  if (blockIdx.x < 2048) {
    // ---- LayerNorm: one wave per row of 512 ----
    const int wid  = threadIdx.x >> 6;
    const int lane = threadIdx.x & 63;
    const int row  = blockIdx.x * 4 + wid;
    const float* xr = x + (size_t)row * DIMD + lane * 8;
    float v[8];
    const float4 a = *reinterpret_cast<const float4*>(xr);
    const float4 b = *reinterpret_cast<const float4*>(xr + 4);
    v[0] = a.x; v[1] = a.y; v[2] = a.z; v[3] = a.w;
    v[4] = b.x; v[5] = b.y; v[6] = b.z; v[7] = b.w;
    float s = 0.f;
#pragma unroll
    for (int i = 0; i < 8; ++i) s += v[i];
#pragma unroll
    for (int off = 32; off; off >>= 1) s += __shfl_down(s, off);
    s = __shfl(s, 0);
    const float mu = s * (1.f / DIMD);
    float ss = 0.f;
#pragma unroll
    for (int i = 0; i < 8; ++i) { float d = v[i] - mu; ss += d * d; }
#pragma unroll
    for (int off = 32; off; off >>= 1) ss += __shfl_down(ss, off);
    ss = __shfl(ss, 0);
    const float inv = rsqrtf(ss * (1.f / DIMD) + 1e-5f);
    const float4 g0 = *reinterpret_cast<const float4*>(gamma + lane * 8);
    const float4 g1 = *reinterpret_cast<const float4*>(gamma + lane * 8 + 4);
    const float4 b0 = *reinterpret_cast<const float4*>(beta + lane * 8);
    const float4 b1 = *reinterpret_cast<const float4*>(beta + lane * 8 + 4);
    float g[8] = {g0.x, g0.y, g0.z, g0.w, g1.x, g1.y, g1.z, g1.w};
    float be[8] = {b0.x, b0.y, b0.z, b0.w, b1.x, b1.y, b1.z, b1.w};
    bf16x8 o;
#pragma unroll
    for (int i = 0; i < 8; ++i)
      o[i] = (short)f2bits((v[i] - mu) * inv * g[i] + be[i]);
    *reinterpret_cast<bf16x8*>(xn + (size_t)row * DIMD + lane * 8) = o;
  } else if (blockIdx.x < 2432) {
    // ---- weight transpose+cvt: in [R][C] fp32 -> out [C][R] bf16 ----
    const int t = blockIdx.x - 2048;
    const int bx = t % 24, rest = t / 24;
    const int by = rest % 8, z = rest / 8;
    const int C = z ? DIMD : QKVN;
    if (z && bx >= DIMD / 64) return;
    const float* in = z ? in1 : in0;
    unsigned short* out = z ? out1 : out0;
    const int r0 = by * 64, c0 = bx * 64;
    const int ty = threadIdx.x >> 4, tx = threadIdx.x & 15;
#pragma unroll
    for (int i = 0; i < 4; ++i) {
      const int r = ty + i * 16;
      const float4 v = *reinterpret_cast<const float4*>(
          in + (size_t)(r0 + r) * C + c0 + tx * 4);
      T[r][tx * 4 + 0] = v.x; T[r][tx * 4 + 1] = v.y;
      T[r][tx * 4 + 2] = v.z; T[r][tx * 4 + 3] = v.w;
    }
    __syncthreads();
#pragma unroll
    for (int i = 0; i < 4; ++i) {
      const int c = ty + i * 16;
      ushort4 o;
      o.x = f2bits(T[tx * 4 + 0][c]); o.y = f2bits(T[tx * 4 + 1][c]);
      o.z = f2bits(T[tx * 4 + 2][c]); o.w = f2bits(T[tx * 4 + 3][c]);
      *reinterpret_cast<ushort4*>(out + (size_t)(c0 + c) * DIMD + r0 + tx * 4) = o;
    }
  } else {
    // ---- pbl = (beta/ln2) * pose_bias, fp32 (key-side softmax bias) ----
    const int t2 = blockIdx.x - 2432;
    const float bl2 = betap[0] * INV_LN2;
    const int idx = t2 * 2048 + threadIdx.x * 8;
    const float4 a = *reinterpret_cast<const float4*>(pb + idx);
    const float4 b = *reinterpret_cast<const float4*>(pb + idx + 4);
    float4 oa = {bl2 * a.x, bl2 * a.y, bl2 * a.z, bl2 * a.w};
    float4 ob = {bl2 * b.x, bl2 * b.y, bl2 * b.z, bl2 * b.w};
    *reinterpret_cast<float4*>(pbl + idx) = oa;
    *reinterpret_cast<float4*>(pbl + idx + 4) = ob;
  }
}

// ---------------- m97-structure gll GEMM for GEMM1 (768 blocks = 3/CU) ----------
// global_load_lds width-16, linear LDS [128][64], XOR-swizzled both sides.
// V-column blocks (tn0>=1024) compute C^T via swapped MFMA operands and store
// straight into vtg. T1 XCD-chunked blockIdx swizzle (768%8==0, bijective):
// each XCD's L2 holds 8 full A-panel rows + the 1.5MB B panel. [R12: kept —
// the GEMMs are panel-reuse-bound and drove the 165->160 total win.]
__device__ __forceinline__ void storeC(float* C, size_t idx, float v) { C[idx] = v; }
__device__ __forceinline__ void storeC(unsigned short* C, size_t idx, float v) { C[idx] = f2bits(v); }

template <typename CT, bool QS>
__global__ __launch_bounds__(256) void ggemm_kernel(
    const unsigned short* __restrict__ A, const unsigned short* __restrict__ Bt,
    CT* __restrict__ C, unsigned short* __restrict__ vtg, int M, int N, int K) {
  __shared__ __align__(16) unsigned short As[128 * 64];
  __shared__ __align__(16) unsigned short Bs[128 * 64];
  const int tid  = threadIdx.x;
  const int wave = tid >> 6, lane = tid & 63;
  const int quad = lane >> 4, l16 = lane & 15;
  const int wr = wave >> 1, wc = wave & 1;
  // ---- XCD-chunked bijective swizzle (nwg divisible by 8) ----
  const int nwg  = gridDim.x * gridDim.y;
  const int orig = blockIdx.y * gridDim.x + blockIdx.x;
  const int swz  = (orig & 7) * (nwg >> 3) + (orig >> 3);
  const int tm0 = (swz / gridDim.x) * 128, tn0 = (swz % gridDim.x) * 128;
  const bool vswap = QS && (tn0 >= 2 * DIMD);   // V-column block
  const int srow = wave * 8 + (lane >> 3);
  const int ssh  = (((lane & 7) * 16) ^ ((lane >> 3) << 4)) >> 1;  // shorts
  const unsigned short* ap = A + (size_t)(tm0 + srow) * K + ssh;
  const unsigned short* bp = Bt + (size_t)(tn0 + srow) * K + ssh;
  const int xs = (l16 & 7) << 3;
  f32x4 acc[4][4];
#pragma unroll
  for (int i = 0; i < 4; ++i)
#pragma unroll
    for (int j = 0; j < 4; ++j) acc[i][j] = (f32x4){0.f, 0.f, 0.f, 0.f};

  for (int k0 = 0; k0 < K; k0 += 64) {
#pragma unroll
    for (int i = 0; i < 4; ++i) {
      gll16(ap + (size_t)(i * 32) * K + k0, &As[i * 2048 + wave * 512]);
      gll16(bp + (size_t)(i * 32) * K + k0, &Bs[i * 2048 + wave * 512]);
    }
    __syncthreads();          // drains vmcnt -> slab valid
#pragma unroll
    for (int kc = 0; kc < 2; ++kc) {
      const int kk = ((kc * 32 + quad * 8) ^ xs);
      bf16x8 af[4], bfr[4];
#pragma unroll
      for (int i = 0; i < 4; ++i)
        af[i] = *reinterpret_cast<const bf16x8*>(&As[(wr * 64 + i * 16 + l16) * 64 + kk]);
#pragma unroll
      for (int j = 0; j < 4; ++j)
        bfr[j] = *reinterpret_cast<const bf16x8*>(&Bs[(wc * 64 + j * 16 + l16) * 64 + kk]);
      if (vswap) {
#pragma unroll
        for (int i = 0; i < 4; ++i)
#pragma unroll
          for (int j = 0; j < 4; ++j)
            acc[i][j] = __builtin_amdgcn_mfma_f32_16x16x32_bf16(bfr[j], af[i], acc[i][j], 0, 0, 0);
      } else {
#pragma unroll
        for (int i = 0; i < 4; ++i)
#pragma unroll
          for (int j = 0; j < 4; ++j)
            acc[i][j] = __builtin_amdgcn_mfma_f32_16x16x32_bf16(af[i], bfr[j], acc[i][j], 0, 0, 0);
      }
    }
    __syncthreads();
  }
  if (vswap) {
    // acc[i][j] = C^T block: rows = C-cols (tn0+wc*64+j*16+quad*4+r),
    //             cols = C-rows (tm0+wr*64+i*16+l16). Store into vtg.
#pragma unroll
    for (int j = 0; j < 4; ++j)
#pragma unroll
      for (int i = 0; i < 4; ++i)
#pragma unroll
        for (int r = 0; r < 4; ++r) {
          const int vcol = tn0 - 2 * DIMD + wc * 64 + j * 16 + quad * 4 + r;
          const int hi = vcol >> 6, d = vcol & 63;
          const int rowc = tm0 + wr * 64 + i * 16 + l16;
          const int bi = rowc >> 11, jc = rowc & (NCTX - 1);
          vtg[((size_t)(bi * NH + hi) * DH + d) * NCTX + jc] = f2bits(acc[i][j][r]);
        }
  } else {
#pragma unroll
    for (int j = 0; j < 4; ++j) {
      const int col = tn0 + wc * 64 + j * 16 + l16;
      const float scl = (QS && col < DIMD) ? SCLOG : 1.0f;
#pragma unroll
      for (int i = 0; i < 4; ++i)
#pragma unroll
        for (int r = 0; r < 4; ++r)
          storeC(C, (size_t)(tm0 + wr * 64 + i * 16 + quad * 4 + r) * N + col,
                 acc[i][j][r] * scl);
    }
  }
}

// ---------------- GEMM2: 128x128 reg-prefetch kernel + T1 swizzle (256%8==0) --
template <typename CT, bool QS>
__global__ __launch_bounds__(256) void mgemm_kernel(
    const unsigned short* __restrict__ A, const unsigned short* __restrict__ Bt,
    CT* __restrict__ C, int M, int N, int K) {
  __shared__ __align__(16) unsigned short As[128][72];
  __shared__ __align__(16) unsigned short Bs[128][72];
  const int tid  = threadIdx.x;
  const int wave = tid >> 6, lane = tid & 63;
  const int quad = lane >> 4, l16 = lane & 15;
  const int wr = wave >> 1, wc = wave & 1;
  const int nwg  = gridDim.x * gridDim.y;
  const int orig = blockIdx.y * gridDim.x + blockIdx.x;
  const int swz  = (orig & 7) * (nwg >> 3) + (orig >> 3);
  const int tm0 = (swz / gridDim.x) * 128, tn0 = (swz % gridDim.x) * 128;
  const int srow = tid >> 3;
  const int schunk = (tid & 7) * 8;
  f32x4 acc[4][4];
#pragma unroll
  for (int i = 0; i < 4; ++i)
#pragma unroll
    for (int j = 0; j < 4; ++j) acc[i][j] = (f32x4){0.f, 0.f, 0.f, 0.f};

  bf16x8 ra[4], rb[4];
#pragma unroll
  for (int p = 0; p < 4; ++p) {
    const int r = srow + p * 32;
    ra[p] = *reinterpret_cast<const bf16x8*>(A + (size_t)(tm0 + r) * K + schunk);
    rb[p] = *reinterpret_cast<const bf16x8*>(Bt + (size_t)(tn0 + r) * K + schunk);
  }
  for (int k0 = 0; k0 < K; k0 += 64) {
#pragma unroll
    for (int p = 0; p < 4; ++p) {
      const int r = srow + p * 32;
      *reinterpret_cast<bf16x8*>(&As[r][schunk]) = ra[p];
      *reinterpret_cast<bf16x8*>(&Bs[r][schunk]) = rb[p];
    }
    __syncthreads();
    if (k0 + 64 < K) {
#pragma unroll
      for (int p = 0; p < 4; ++p) {
        const int r = srow + p * 32;
        ra[p] = *reinterpret_cast<const bf16x8*>(A + (size_t)(tm0 + r) * K + k0 + 64 + schunk);
        rb[p] = *reinterpret_cast<const bf16x8*>(Bt + (size_t)(tn0 + r) * K + k0 + 64 + schunk);
      }
    }
#pragma unroll
    for (int kc = 0; kc < 2; ++kc) {
      const int kk = kc * 32 + quad * 8;
      bf16x8 af[4], bfr[4];
#pragma unroll
      for (int i = 0; i < 4; ++i)
        af[i] = *reinterpret_cast<const bf16x8*>(&As[wr * 64 + i * 16 + l16][kk]);
#pragma unroll
      for (int j = 0; j < 4; ++j)
        bfr[j] = *reinterpret_cast<const bf16x8*>(&Bs[wc * 64 + j * 16 + l16][kk]);
#pragma unroll
      for (int i = 0; i < 4; ++i)
#pragma unroll
        for (int j = 0; j < 4; ++j)
          acc[i][j] = __builtin_amdgcn_mfma_f32_16x16x32_bf16(af[i], bfr[j], acc[i][j], 0, 0, 0);
    }
    __syncthreads();
  }
#pragma unroll
  for (int j = 0; j < 4; ++j) {
    const int col = tn0 + wc * 64 + j * 16 + l16;
    const float scl = (QS && col < DIMD) ? SCLOG : 1.0f;
#pragma unroll
    for (int i = 0; i < 4; ++i)
#pragma unroll
      for (int r = 0; r < 4; ++r)
        storeC(C, (size_t)(tm0 + wr * 64 + i * 16 + quad * 4 + r) * N + col,
               acc[i][j][r] * scl);
  }
}

// ---------------- MFMA flash attention: 2x2 wave split, gll double-buffer ------
// Round 26 == Round 25 resubmitted (R13 bench was an infrastructure failure —
// container died twice; no kernel verdict). Change vs R12 still under test:
// fattn XCD swizzle REVERTED (R12: FETCH 69.8->12.4MB but dur 54.2->56.5 —
// fattn is not BW-bound; remap cost ~2.3us). Natural blockIdx mapping restored;
// GEMM swizzles kept (they drove the 165->160 win). Loop: R10 __syncthreads
// form (best measured fattn: 54.2).
__global__ __launch_bounds__(256, 4) void fattn_kernel(
    const unsigned short* __restrict__ qkv,   // [NROWS, 1536] bf16 (Q pre-scaled by SCLOG)
    const unsigned short* __restrict__ vtg,   // [NB*NH*64][2048] bf16 (unscaled V^T)
    const float* __restrict__ pbl,            // [NB*NCTX] fp32 = bl2*pose_bias
    unsigned short* __restrict__ out) {       // [NROWS, 512] bf16
  // per buffer (shorts): K [64][64] @0, V [64][64] @4096, pbl fp32[64] @8192
  __shared__ __align__(16) unsigned short lds[2][8320];

  const int qt = blockIdx.x, hi = blockIdx.y, bi = blockIdx.z;
  const int tid  = threadIdx.x;
  const int wave = tid >> 6, lane = tid & 63;
  const int quad = lane >> 4, l16 = lane & 15;
  const int wq = wave & 1, wk = wave >> 1;
  const int qrow0 = qt * 64;
  const unsigned short* base  = qkv + (size_t)bi * NCTX * QKVN + hi * DH;
  const unsigned short* vbase = vtg + (size_t)(bi * NH + hi) * DH * NCTX;
  const float* pbase = pbl + (size_t)bi * NCTX;

  // ---- staging decomposition: per gll inst, wave covers 8 rows x 128B ----
  const int sr8 = lane >> 3;                                    // row&7
  const int ssh = ((((lane & 7) * 16) ^ (sr8 << 4)) >> 1);      // swz src (shorts)
  const unsigned short* kp0 = base + (size_t)(wave * 8 + sr8) * QKVN + DIMD + ssh;
  const unsigned short* kp1 = kp0 + (size_t)32 * QKVN;
  const unsigned short* vp0 = vbase + (size_t)(wave * 8 + sr8) * NCTX + ssh;
  const unsigned short* vp1 = vp0 + (size_t)32 * NCTX;
  const float* pp = pbase + lane;

#define STAGE(buf)                                    \
  gll16(kp0, &(buf)[wave * 512]);                     \
  gll16(kp1, &(buf)[2048 + wave * 512]);              \
  gll16(vp0, &(buf)[4096 + wave * 512]);              \
  gll16(vp1, &(buf)[6144 + wave * 512]);              \
  if (tid < 64) gll4(pp, &(buf)[8192]);               \
  kp0 += (size_t)64 * QKVN; kp1 += (size_t)64 * QKVN; \
  vp0 += 64; vp1 += 64; pp += 64;

  // ---- Q B-frags straight from global (one-time) ----
  bf16x8 qf[2][2];
#pragma unroll
  for (int u = 0; u < 2; ++u)
#pragma unroll
    for (int h = 0; h < 2; ++h)
      qf[u][h] = *reinterpret_cast<const bf16x8*>(
          base + (size_t)(qrow0 + wq * 32 + u * 16 + l16) * QKVN + h * 32 + quad * 8);

  // ---- read-side offsets (swizzled; row&7 == l16&7 for all frag reads) ----
  const int xs = (l16 & 7) << 3;
  const int kofs0 = (wk * 32 + l16) * 64 + ((quad * 8) ^ xs);        // t adds 1024
  const int kofs1 = (wk * 32 + l16) * 64 + ((32 + quad * 8) ^ xs);
  const int vofs  = 4096 + l16 * 64 + ((wk * 32 + quad * 8) ^ xs);   // s adds 1024
  const int pofs  = wk * 32 + quad * 4;                              // fp32 idx; t adds 16

  // ---- ones fragment: bf16(1.0) splat (denominator B-operand) ----
  const bf16x8 ones = {16256, 16256, 16256, 16256, 16256, 16256, 16256, 16256};

  // ---- prologue: stage tile 0 ----
  STAGE(lds[0]);
  __syncthreads();

  f32x4 O[2][4], accl[2];
#pragma unroll
  for (int u = 0; u < 2; ++u) {
    accl[u] = (f32x4){0.f, 0.f, 0.f, 0.f};
#pragma unroll
    for (int s = 0; s < 4; ++s) O[u][s] = (f32x4){0.f, 0.f, 0.f, 0.f};
  }

  for (int kt = 0; kt < 32; ++kt) {
    const unsigned short* bc = lds[kt & 1];
    if (kt < 31) { STAGE(lds[(kt & 1) ^ 1]); }   // DMA into other buffer
    const float* pblf = (const float*)(bc + 8192);
    // ---- S^T = K Q^T + bias on wave's 32 keys x 32 queries ----
    f32x4 sfr[2][2];   // [t key-sub][u query-sub]
#pragma unroll
    for (int t = 0; t < 2; ++t) {
      const bf16x8 kf0 = *reinterpret_cast<const bf16x8*>(&bc[kofs0 + t * 1024]);
      const bf16x8 kf1 = *reinterpret_cast<const bf16x8*>(&bc[kofs1 + t * 1024]);
      const f32x4 bias = *reinterpret_cast<const f32x4*>(&pblf[pofs + t * 16]);
#pragma unroll
      for (int u = 0; u < 2; ++u) {
        f32x4 acc = bias;   // key-side softmax bias enters as C-operand
        acc = __builtin_amdgcn_mfma_f32_16x16x32_bf16(kf0, qf[u][0], acc, 0, 0, 0);
        acc = __builtin_amdgcn_mfma_f32_16x16x32_bf16(kf1, qf[u][1], acc, 0, 0, 0);
        sfr[t][u] = acc;
      }
    }
    // ---- P = exp2(S): raw v_exp_f32 -> compiled cvt_pk_bf16 pairs,
    // ---- then permlane redistribution (asm inputs are plain-VALU results) ----
    bf16x8 pf[2];
#pragma unroll
    for (int u = 0; u < 2; ++u) {
      unsigned x0 = pk2(__builtin_amdgcn_exp2f(sfr[0][u][0]),
                        __builtin_amdgcn_exp2f(sfr[0][u][1]));
      unsigned x1 = pk2(__builtin_amdgcn_exp2f(sfr[0][u][2]),
                        __builtin_amdgcn_exp2f(sfr[0][u][3]));
      unsigned y0 = pk2(__builtin_amdgcn_exp2f(sfr[1][u][0]),
                        __builtin_amdgcn_exp2f(sfr[1][u][1]));
      unsigned y1 = pk2(__builtin_amdgcn_exp2f(sfr[1][u][2]),
                        __builtin_amdgcn_exp2f(sfr[1][u][3]));
      asm("v_permlane32_swap_b32 %0, %1" : "+v"(x0), "+v"(y0));
      asm("v_permlane32_swap_b32 %0, %1" : "+v"(x1), "+v"(y1));
      asm("v_permlane16_swap_b32 %0, %1" : "+v"(x0), "+v"(y0));
      asm("v_permlane16_swap_b32 %0, %1" : "+v"(x1), "+v"(y1));
      union { unsigned q[4]; bf16x8 v; } pu;
      pu.q[0] = x0; pu.q[1] = x1; pu.q[2] = y0; pu.q[3] = y1;
      pf[u] = pu.v;
    }
    // ---- O += P V' over wave's keys; denominator via ones-fragment ----
    {
      accl[0] = __builtin_amdgcn_mfma_f32_16x16x32_bf16(pf[0], ones, accl[0], 0, 0, 0);
      accl[1] = __builtin_amdgcn_mfma_f32_16x16x32_bf16(pf[1], ones, accl[1], 0, 0, 0);
#pragma unroll
      for (int s = 0; s < 4; ++s) {
        const bf16x8 bv = *reinterpret_cast<const bf16x8*>(&bc[vofs + s * 1024]);
        O[0][s] = __builtin_amdgcn_mfma_f32_16x16x32_bf16(pf[0], bv, O[0][s], 0, 0, 0);
        O[1][s] = __builtin_amdgcn_mfma_f32_16x16x32_bf16(pf[1], bv, O[1][s], 0, 0, 0);
      }
    }
    __syncthreads();   // drains gll vmcnt -> next buffer valid; closes reads of bc
  }
#undef STAGE
  // ---- combine key-halves via Ob (bf16, stride 68) + lb (fp32), alias lds ----
  unsigned short* Ob = (unsigned short*)lds;
  float* lb = (float*)((unsigned short*)lds + 4352);
  if (wk == 1) {
#pragma unroll
    for (int u = 0; u < 2; ++u) {
#pragma unroll
      for (int s = 0; s < 4; ++s)
#pragma unroll
        for (int r = 0; r < 4; ++r)
          Ob[(wq * 32 + u * 16 + quad * 4 + r) * 68 + s * 16 + l16] = f2bits(O[u][s][r]);
      if (l16 == 0)
#pragma unroll
        for (int r = 0; r < 4; ++r)
          lb[64 + wq * 32 + u * 16 + quad * 4 + r] = accl[u][r];
    }
  } else {
#pragma unroll
    for (int u = 0; u < 2; ++u)
      if (l16 == 0)
#pragma unroll
        for (int r = 0; r < 4; ++r)
          lb[wq * 32 + u * 16 + quad * 4 + r] = accl[u][r];
  }
  __syncthreads();
  if (wk == 0) {
#pragma unroll
    for (int u = 0; u < 2; ++u)
#pragma unroll
      for (int r = 0; r < 4; ++r) {
        const int ql = wq * 32 + u * 16 + quad * 4 + r;
        const float linv = 1.f / (lb[ql] + lb[64 + ql]);
        const size_t orow = ((size_t)bi * NCTX + qrow0 + ql) * DIMD + hi * DH;
#pragma unroll
        for (int s = 0; s < 4; ++s)
          out[orow + s * 16 + l16] =
              f2bits((O[u][s][r] + bits2f(Ob[ql * 68 + s * 16 + l16])) * linv);
      }
  }
}

extern "C" void kernel_launch(void* const* d_in, const int* in_sizes, int n_in,
                              void* d_out, int out_size, void* d_ws, size_t ws_size,
                              hipStream_t stream) {
  const float* x     = (const float*)d_in[0];
  const float* pose  = (const float*)d_in[1];
  const float* gam   = (const float*)d_in[2];
  const float* bet   = (const float*)d_in[3];
  const float* wqkv  = (const float*)d_in[4];
  const float* wout  = (const float*)d_in[5];
  const float* betap = (const float*)d_in[6];
  float* out = (float*)d_out;

  unsigned short* xn    = (unsigned short*)d_ws;             // 8 MB (reused as aout)
  unsigned short* qkvb  = xn + (size_t)NROWS * DIMD;         // 24 MB
  unsigned short* wqkvT = qkvb + (size_t)NROWS * QKVN;       // 1.5 MB
  unsigned short* woutT = wqkvT + (size_t)QKVN * DIMD;       // 0.5 MB
  unsigned short* vtg   = woutT + (size_t)DIMD * DIMD;       // 8 MB  V^T (from ggemm1)
  float*          pbl   = (float*)(vtg + (size_t)NB * NH * DH * NCTX); // 32 KB
  unsigned short* aout  = xn;                                // alias: xn dead after GEMM1

  lntc_kernel<<<2048 + 384 + 4, 256, 0, stream>>>(
      x, gam, bet, xn, wqkv, wqkvT, wout, woutT, pose, betap, pbl);
  ggemm_kernel<unsigned short, true><<<dim3(QKVN / 128, NROWS / 128), 256, 0, stream>>>(
      xn, wqkvT, qkvb, vtg, NROWS, QKVN, DIMD);
  fattn_kernel<<<dim3(NCTX / 64, NH, NB), 256, 0, stream>>>(qkvb, vtg, pbl, aout);
  mgemm_kernel<float, false><<<dim3(DIMD / 128, NROWS / 128), 256, 0, stream>>>(
      aout, woutT, out, NROWS, DIMD, DIMD);
}

// Round 15
// 159.304 us; speedup vs baseline: 1.0461x; 1.0461x over previous
//
#include <hip/hip_runtime.h>
#include <hip/hip_bf16.h>

#define NH    8
#define DH    64
#define DIMD  512
#define NCTX  2048
#define NB    4
#define NROWS (NB * NCTX)   // 8192
#define QKVN  (3 * DIMD)    // 1536

typedef __attribute__((ext_vector_type(8))) short bf16x8;
typedef __attribute__((ext_vector_type(4))) float f32x4;

#define INV_LN2 1.44269504f
#define SCLOG   (0.125f * INV_LN2)   // folded into Q at mgemm1 epilogue

__device__ __forceinline__ unsigned short f2bits(float f) {
  unsigned u = __float_as_uint(f);
  u += 0x7fffu + ((u >> 16) & 1u);      // round-to-nearest-even
  return (unsigned short)(u >> 16);
}
__device__ __forceinline__ float bits2f(unsigned short u) {
  return __uint_as_float(((unsigned)u) << 16);
}
// packed bf16 pair via compiled cvt_pk (RTNE; hazard-safe consumer of v_exp)
__device__ __forceinline__ unsigned pk2(float lo, float hi) {
  __hip_bfloat162 h = __float22bfloat162_rn(float2{lo, hi});
  union { __hip_bfloat162 h; unsigned u; } c; c.h = h; return c.u;
}

// ---- global_load_lds wrappers (width 16 / 4). LDS base must be wave-uniform;
// ---- global src is per-lane (pre-swizzled source = swizzled LDS, rule #21).
__device__ __forceinline__ void gll16(const void* g, void* l) {
  __builtin_amdgcn_global_load_lds(
      (const __attribute__((address_space(1))) unsigned int*)g,
      (__attribute__((address_space(3))) unsigned int*)l, 16, 0, 0);
}
__device__ __forceinline__ void gll4(const void* g, void* l) {
  __builtin_amdgcn_global_load_lds(
      (const __attribute__((address_space(1))) unsigned int*)g,
      (__attribute__((address_space(3))) unsigned int*)l, 4, 0, 0);
}

// -------- Merged LayerNorm + weight-transpose + pose-bias prep (one launch) --
// blocks [0,2048): LN rows; [2048,2432): tconv tiles; [2432,2436): pbl.
__global__ __launch_bounds__(256) void lntc_kernel(
    const float* __restrict__ x,
    const float* __restrict__ gamma,
    const float* __restrict__ beta,
    unsigned short* __restrict__ xn,
    const float* __restrict__ in0, unsigned short* __restrict__ out0,
    const float* __restrict__ in1, unsigned short* __restrict__ out1,
    const float* __restrict__ pb, const float* __restrict__ betap,
    float* __restrict__ pbl) {
  __shared__ float T[64][65];
  if (blockIdx.x < 2048) {
    // ---- LayerNorm: one wave per row of 512 ----
    const int wid  = threadIdx.x >> 6;
    const int lane = threadIdx.x & 63;
    const int row  = blockIdx.x * 4 + wid;
    const float* xr = x + (size_t)row * DIMD + lane * 8;
    float v[8];
    const float4 a = *reinterpret_cast<const float4*>(xr);
    const float4 b = *reinterpret_cast<const float4*>(xr + 4);
    v[0] = a.x; v[1] = a.y; v[2] = a.z; v[3] = a.w;
    v[4] = b.x; v[5] = b.y; v[6] = b.z; v[7] = b.w;
    float s = 0.f;
#pragma unroll
    for (int i = 0; i < 8; ++i) s += v[i];
#pragma unroll
    for (int off = 32; off; off >>= 1) s += __shfl_down(s, off);
    s = __shfl(s, 0);
    const float mu = s * (1.f / DIMD);
    float ss = 0.f;
#pragma unroll
    for (int i = 0; i < 8; ++i) { float d = v[i] - mu; ss += d * d; }
#pragma unroll
    for (int off = 32; off; off >>= 1) ss += __shfl_down(ss, off);
    ss = __shfl(ss, 0);
    const float inv = rsqrtf(ss * (1.f / DIMD) + 1e-5f);
    const float4 g0 = *reinterpret_cast<const float4*>(gamma + lane * 8);
    const float4 g1 = *reinterpret_cast<const float4*>(gamma + lane * 8 + 4);
    const float4 b0 = *reinterpret_cast<const float4*>(beta + lane * 8);
    const float4 b1 = *reinterpret_cast<const float4*>(beta + lane * 8 + 4);
    float g[8] = {g0.x, g0.y, g0.z, g0.w, g1.x, g1.y, g1.z, g1.w};
    float be[8] = {b0.x, b0.y, b0.z, b0.w, b1.x, b1.y, b1.z, b1.w};
    bf16x8 o;
#pragma unroll
    for (int i = 0; i < 8; ++i)
      o[i] = (short)f2bits((v[i] - mu) * inv * g[i] + be[i]);
    *reinterpret_cast<bf16x8*>(xn + (size_t)row * DIMD + lane * 8) = o;
  } else if (blockIdx.x < 2432) {
    // ---- weight transpose+cvt: in [R][C] fp32 -> out [C][R] bf16 ----
    const int t = blockIdx.x - 2048;
    const int bx = t % 24, rest = t / 24;
    const int by = rest % 8, z = rest / 8;
    const int C = z ? DIMD : QKVN;
    if (z && bx >= DIMD / 64) return;
    const float* in = z ? in1 : in0;
    unsigned short* out = z ? out1 : out0;
    const int r0 = by * 64, c0 = bx * 64;
    const int ty = threadIdx.x >> 4, tx = threadIdx.x & 15;
#pragma unroll
    for (int i = 0; i < 4; ++i) {
      const int r = ty + i * 16;
      const float4 v = *reinterpret_cast<const float4*>(
          in + (size_t)(r0 + r) * C + c0 + tx * 4);
      T[r][tx * 4 + 0] = v.x; T[r][tx * 4 + 1] = v.y;
      T[r][tx * 4 + 2] = v.z; T[r][tx * 4 + 3] = v.w;
    }
    __syncthreads();
#pragma unroll
    for (int i = 0; i < 4; ++i) {
      const int c = ty + i * 16;
      ushort4 o;
      o.x = f2bits(T[tx * 4 + 0][c]); o.y = f2bits(T[tx * 4 + 1][c]);
      o.z = f2bits(T[tx * 4 + 2][c]); o.w = f2bits(T[tx * 4 + 3][c]);
      *reinterpret_cast<ushort4*>(out + (size_t)(c0 + c) * DIMD + r0 + tx * 4) = o;
    }
  } else {
    // ---- pbl = (beta/ln2) * pose_bias, fp32 (key-side softmax bias) ----
    const int t2 = blockIdx.x - 2432;
    const float bl2 = betap[0] * INV_LN2;
    const int idx = t2 * 2048 + threadIdx.x * 8;
    const float4 a = *reinterpret_cast<const float4*>(pb + idx);
    const float4 b = *reinterpret_cast<const float4*>(pb + idx + 4);
    float4 oa = {bl2 * a.x, bl2 * a.y, bl2 * a.z, bl2 * a.w};
    float4 ob = {bl2 * b.x, bl2 * b.y, bl2 * b.z, bl2 * b.w};
    *reinterpret_cast<float4*>(pbl + idx) = oa;
    *reinterpret_cast<float4*>(pbl + idx + 4) = ob;
  }
}

// ---------------- m97-structure gll GEMM for GEMM1 (768 blocks = 3/CU) ----------
// global_load_lds width-16, linear LDS [128][64], XOR-swizzled both sides.
// V-column blocks (tn0>=1024) compute C^T via swapped MFMA operands and store
// straight into vtg. T1 XCD-chunked blockIdx swizzle kept (within-noise but
// mechanism-correct for panel reuse).
__device__ __forceinline__ void storeC(float* C, size_t idx, float v) { C[idx] = v; }
__device__ __forceinline__ void storeC(unsigned short* C, size_t idx, float v) { C[idx] = f2bits(v); }

template <typename CT, bool QS>
__global__ __launch_bounds__(256) void ggemm_kernel(
    const unsigned short* __restrict__ A, const unsigned short* __restrict__ Bt,
    CT* __restrict__ C, unsigned short* __restrict__ vtg, int M, int N, int K) {
  __shared__ __align__(16) unsigned short As[128 * 64];
  __shared__ __align__(16) unsigned short Bs[128 * 64];
  const int tid  = threadIdx.x;
  const int wave = tid >> 6, lane = tid & 63;
  const int quad = lane >> 4, l16 = lane & 15;
  const int wr = wave >> 1, wc = wave & 1;
  // ---- XCD-chunked bijective swizzle (nwg divisible by 8) ----
  const int nwg  = gridDim.x * gridDim.y;
  const int orig = blockIdx.y * gridDim.x + blockIdx.x;
  const int swz  = (orig & 7) * (nwg >> 3) + (orig >> 3);
  const int tm0 = (swz / gridDim.x) * 128, tn0 = (swz % gridDim.x) * 128;
  const bool vswap = QS && (tn0 >= 2 * DIMD);   // V-column block
  const int srow = wave * 8 + (lane >> 3);
  const int ssh  = (((lane & 7) * 16) ^ ((lane >> 3) << 4)) >> 1;  // shorts
  const unsigned short* ap = A + (size_t)(tm0 + srow) * K + ssh;
  const unsigned short* bp = Bt + (size_t)(tn0 + srow) * K + ssh;
  const int xs = (l16 & 7) << 3;
  f32x4 acc[4][4];
#pragma unroll
  for (int i = 0; i < 4; ++i)
#pragma unroll
    for (int j = 0; j < 4; ++j) acc[i][j] = (f32x4){0.f, 0.f, 0.f, 0.f};

  for (int k0 = 0; k0 < K; k0 += 64) {
#pragma unroll
    for (int i = 0; i < 4; ++i) {
      gll16(ap + (size_t)(i * 32) * K + k0, &As[i * 2048 + wave * 512]);
      gll16(bp + (size_t)(i * 32) * K + k0, &Bs[i * 2048 + wave * 512]);
    }
    __syncthreads();          // drains vmcnt -> slab valid
#pragma unroll
    for (int kc = 0; kc < 2; ++kc) {
      const int kk = ((kc * 32 + quad * 8) ^ xs);
      bf16x8 af[4], bfr[4];
#pragma unroll
      for (int i = 0; i < 4; ++i)
        af[i] = *reinterpret_cast<const bf16x8*>(&As[(wr * 64 + i * 16 + l16) * 64 + kk]);
#pragma unroll
      for (int j = 0; j < 4; ++j)
        bfr[j] = *reinterpret_cast<const bf16x8*>(&Bs[(wc * 64 + j * 16 + l16) * 64 + kk]);
      if (vswap) {
#pragma unroll
        for (int i = 0; i < 4; ++i)
#pragma unroll
          for (int j = 0; j < 4; ++j)
            acc[i][j] = __builtin_amdgcn_mfma_f32_16x16x32_bf16(bfr[j], af[i], acc[i][j], 0, 0, 0);
      } else {
#pragma unroll
        for (int i = 0; i < 4; ++i)
#pragma unroll
          for (int j = 0; j < 4; ++j)
            acc[i][j] = __builtin_amdgcn_mfma_f32_16x16x32_bf16(af[i], bfr[j], acc[i][j], 0, 0, 0);
      }
    }
    __syncthreads();
  }
  if (vswap) {
#pragma unroll
    for (int j = 0; j < 4; ++j)
#pragma unroll
      for (int i = 0; i < 4; ++i)
#pragma unroll
        for (int r = 0; r < 4; ++r) {
          const int vcol = tn0 - 2 * DIMD + wc * 64 + j * 16 + quad * 4 + r;
          const int hi = vcol >> 6, d = vcol & 63;
          const int rowc = tm0 + wr * 64 + i * 16 + l16;
          const int bi = rowc >> 11, jc = rowc & (NCTX - 1);
          vtg[((size_t)(bi * NH + hi) * DH + d) * NCTX + jc] = f2bits(acc[i][j][r]);
        }
  } else {
#pragma unroll
    for (int j = 0; j < 4; ++j) {
      const int col = tn0 + wc * 64 + j * 16 + l16;
      const float scl = (QS && col < DIMD) ? SCLOG : 1.0f;
#pragma unroll
      for (int i = 0; i < 4; ++i)
#pragma unroll
        for (int r = 0; r < 4; ++r)
          storeC(C, (size_t)(tm0 + wr * 64 + i * 16 + quad * 4 + r) * N + col,
                 acc[i][j][r] * scl);
    }
  }
}

// ---------------- GEMM2: 128x128 reg-prefetch kernel + T1 swizzle (256%8==0) --
template <typename CT, bool QS>
__global__ __launch_bounds__(256) void mgemm_kernel(
    const unsigned short* __restrict__ A, const unsigned short* __restrict__ Bt,
    CT* __restrict__ C, int M, int N, int K) {
  __shared__ __align__(16) unsigned short As[128][72];
  __shared__ __align__(16) unsigned short Bs[128][72];
  const int tid  = threadIdx.x;
  const int wave = tid >> 6, lane = tid & 63;
  const int quad = lane >> 4, l16 = lane & 15;
  const int wr = wave >> 1, wc = wave & 1;
  const int nwg  = gridDim.x * gridDim.y;
  const int orig = blockIdx.y * gridDim.x + blockIdx.x;
  const int swz  = (orig & 7) * (nwg >> 3) + (orig >> 3);
  const int tm0 = (swz / gridDim.x) * 128, tn0 = (swz % gridDim.x) * 128;
  const int srow = tid >> 3;
  const int schunk = (tid & 7) * 8;
  f32x4 acc[4][4];
#pragma unroll
  for (int i = 0; i < 4; ++i)
#pragma unroll
    for (int j = 0; j < 4; ++j) acc[i][j] = (f32x4){0.f, 0.f, 0.f, 0.f};

  bf16x8 ra[4], rb[4];
#pragma unroll
  for (int p = 0; p < 4; ++p) {
    const int r = srow + p * 32;
    ra[p] = *reinterpret_cast<const bf16x8*>(A + (size_t)(tm0 + r) * K + schunk);
    rb[p] = *reinterpret_cast<const bf16x8*>(Bt + (size_t)(tn0 + r) * K + schunk);
  }
  for (int k0 = 0; k0 < K; k0 += 64) {
#pragma unroll
    for (int p = 0; p < 4; ++p) {
      const int r = srow + p * 32;
      *reinterpret_cast<bf16x8*>(&As[r][schunk]) = ra[p];
      *reinterpret_cast<bf16x8*>(&Bs[r][schunk]) = rb[p];
    }
    __syncthreads();
    if (k0 + 64 < K) {
#pragma unroll
      for (int p = 0; p < 4; ++p) {
        const int r = srow + p * 32;
        ra[p] = *reinterpret_cast<const bf16x8*>(A + (size_t)(tm0 + r) * K + k0 + 64 + schunk);
        rb[p] = *reinterpret_cast<const bf16x8*>(Bt + (size_t)(tn0 + r) * K + k0 + 64 + schunk);
      }
    }
#pragma unroll
    for (int kc = 0; kc < 2; ++kc) {
      const int kk = kc * 32 + quad * 8;
      bf16x8 af[4], bfr[4];
#pragma unroll
      for (int i = 0; i < 4; ++i)
        af[i] = *reinterpret_cast<const bf16x8*>(&As[wr * 64 + i * 16 + l16][kk]);
#pragma unroll
      for (int j = 0; j < 4; ++j)
        bfr[j] = *reinterpret_cast<const bf16x8*>(&Bs[wc * 64 + j * 16 + l16][kk]);
#pragma unroll
      for (int i = 0; i < 4; ++i)
#pragma unroll
        for (int j = 0; j < 4; ++j)
          acc[i][j] = __builtin_amdgcn_mfma_f32_16x16x32_bf16(af[i], bfr[j], acc[i][j], 0, 0, 0);
    }
    __syncthreads();
  }
#pragma unroll
  for (int j = 0; j < 4; ++j) {
    const int col = tn0 + wc * 64 + j * 16 + l16;
    const float scl = (QS && col < DIMD) ? SCLOG : 1.0f;
#pragma unroll
    for (int i = 0; i < 4; ++i)
#pragma unroll
      for (int r = 0; r < 4; ++r)
        storeC(C, (size_t)(tm0 + wr * 64 + i * 16 + quad * 4 + r) * N + col,
               acc[i][j][r] * scl);
  }
}

// ---------------- MFMA flash attention: QBLK=128, 4x2 wave split --------------
// Round 27: query-block doubled 64->128 (512 threads, 8 waves = 4 wq x 2 wk).
// Per-wave shape unchanged (32q x 32k: VGPR/main-loop byte-identical); K/V now
// staged once per 128 queries (staging traffic AND barrier count per CU halve).
// Grid 512 = 2 blocks/CU x 8 waves = same 16 waves/CU. Epilogue extended to
// 128 rows (Ob[128][68]+lb[256] = 9216 shorts < 16640 LDS shorts).
__global__ __launch_bounds__(512, 4) void fattn_kernel(
    const unsigned short* __restrict__ qkv,   // [NROWS, 1536] bf16 (Q pre-scaled by SCLOG)
    const unsigned short* __restrict__ vtg,   // [NB*NH*64][2048] bf16 (unscaled V^T)
    const float* __restrict__ pbl,            // [NB*NCTX] fp32 = bl2*pose_bias
    unsigned short* __restrict__ out) {       // [NROWS, 512] bf16
  // per buffer (shorts): K [64][64] @0, V [64][64] @4096, pbl fp32[64] @8192
  __shared__ __align__(16) unsigned short lds[2][8320];

  const int qt = blockIdx.x, hi = blockIdx.y, bi = blockIdx.z;
  const int tid  = threadIdx.x;
  const int wave = tid >> 6, lane = tid & 63;
  const int quad = lane >> 4, l16 = lane & 15;
  const int wq = wave & 3, wk = wave >> 2;
  const int qrow0 = qt * 128;
  const unsigned short* base  = qkv + (size_t)bi * NCTX * QKVN + hi * DH;
  const unsigned short* vbase = vtg + (size_t)(bi * NH + hi) * DH * NCTX;
  const float* pbase = pbl + (size_t)bi * NCTX;

  // ---- staging: 8 waves x 2 gll16 (wave covers 8 K-rows + 8 V-rows) ----
  const int sr8 = lane >> 3;                                    // row&7
  const int ssh = ((((lane & 7) * 16) ^ (sr8 << 4)) >> 1);      // swz src (shorts)
  const unsigned short* kp0 = base + (size_t)(wave * 8 + sr8) * QKVN + DIMD + ssh;
  const unsigned short* vp0 = vbase + (size_t)(wave * 8 + sr8) * NCTX + ssh;
  const float* pp = pbase + lane;

#define STAGE(buf)                                    \
  gll16(kp0, &(buf)[wave * 512]);                     \
  gll16(vp0, &(buf)[4096 + wave * 512]);              \
  if (tid < 64) gll4(pp, &(buf)[8192]);               \
  kp0 += (size_t)64 * QKVN; vp0 += 64; pp += 64;

  // ---- Q B-frags straight from global (one-time; per-wave 32 queries) ----
  bf16x8 qf[2][2];
#pragma unroll
  for (int u = 0; u < 2; ++u)
#pragma unroll
    for (int h = 0; h < 2; ++h)
      qf[u][h] = *reinterpret_cast<const bf16x8*>(
          base + (size_t)(qrow0 + wq * 32 + u * 16 + l16) * QKVN + h * 32 + quad * 8);

  // ---- read-side offsets (swizzled; row&7 == l16&7 for all frag reads) ----
  const int xs = (l16 & 7) << 3;
  const int kofs0 = (wk * 32 + l16) * 64 + ((quad * 8) ^ xs);        // t adds 1024
  const int kofs1 = (wk * 32 + l16) * 64 + ((32 + quad * 8) ^ xs);
  const int vofs  = 4096 + l16 * 64 + ((wk * 32 + quad * 8) ^ xs);   // s adds 1024
  const int pofs  = wk * 32 + quad * 4;                              // fp32 idx; t adds 16

  // ---- ones fragment: bf16(1.0) splat (denominator B-operand) ----
  const bf16x8 ones = {16256, 16256, 16256, 16256, 16256, 16256, 16256, 16256};

  // ---- prologue: stage tile 0 ----
  STAGE(lds[0]);
  __syncthreads();

  f32x4 O[2][4], accl[2];
#pragma unroll
  for (int u = 0; u < 2; ++u) {
    accl[u] = (f32x4){0.f, 0.f, 0.f, 0.f};
#pragma unroll
    for (int s = 0; s < 4; ++s) O[u][s] = (f32x4){0.f, 0.f, 0.f, 0.f};
  }

  for (int kt = 0; kt < 32; ++kt) {
    const unsigned short* bc = lds[kt & 1];
    if (kt < 31) { STAGE(lds[(kt & 1) ^ 1]); }   // DMA into other buffer
    const float* pblf = (const float*)(bc + 8192);
    // ---- S^T = K Q^T + bias on wave's 32 keys x 32 queries ----
    f32x4 sfr[2][2];   // [t key-sub][u query-sub]
#pragma unroll
    for (int t = 0; t < 2; ++t) {
      const bf16x8 kf0 = *reinterpret_cast<const bf16x8*>(&bc[kofs0 + t * 1024]);
      const bf16x8 kf1 = *reinterpret_cast<const bf16x8*>(&bc[kofs1 + t * 1024]);
      const f32x4 bias = *reinterpret_cast<const f32x4*>(&pblf[pofs + t * 16]);
#pragma unroll
      for (int u = 0; u < 2; ++u) {
        f32x4 acc = bias;   // key-side softmax bias enters as C-operand
        acc = __builtin_amdgcn_mfma_f32_16x16x32_bf16(kf0, qf[u][0], acc, 0, 0, 0);
        acc = __builtin_amdgcn_mfma_f32_16x16x32_bf16(kf1, qf[u][1], acc, 0, 0, 0);
        sfr[t][u] = acc;
      }
    }
    // ---- P = exp2(S): raw v_exp_f32 -> compiled cvt_pk_bf16 pairs,
    // ---- then permlane redistribution (asm inputs are plain-VALU results) ----
    bf16x8 pf[2];
#pragma unroll
    for (int u = 0; u < 2; ++u) {
      unsigned x0 = pk2(__builtin_amdgcn_exp2f(sfr[0][u][0]),
                        __builtin_amdgcn_exp2f(sfr[0][u][1]));
      unsigned x1 = pk2(__builtin_amdgcn_exp2f(sfr[0][u][2]),
                        __builtin_amdgcn_exp2f(sfr[0][u][3]));
      unsigned y0 = pk2(__builtin_amdgcn_exp2f(sfr[1][u][0]),
                        __builtin_amdgcn_exp2f(sfr[1][u][1]));
      unsigned y1 = pk2(__builtin_amdgcn_exp2f(sfr[1][u][2]),
                        __builtin_amdgcn_exp2f(sfr[1][u][3]));
      asm("v_permlane32_swap_b32 %0, %1" : "+v"(x0), "+v"(y0));
      asm("v_permlane32_swap_b32 %0, %1" : "+v"(x1), "+v"(y1));
      asm("v_permlane16_swap_b32 %0, %1" : "+v"(x0), "+v"(y0));
      asm("v_permlane16_swap_b32 %0, %1" : "+v"(x1), "+v"(y1));
      union { unsigned q[4]; bf16x8 v; } pu;
      pu.q[0] = x0; pu.q[1] = x1; pu.q[2] = y0; pu.q[3] = y1;
      pf[u] = pu.v;
    }
    // ---- O += P V' over wave's keys; denominator via ones-fragment ----
    {
      accl[0] = __builtin_amdgcn_mfma_f32_16x16x32_bf16(pf[0], ones, accl[0], 0, 0, 0);
      accl[1] = __builtin_amdgcn_mfma_f32_16x16x32_bf16(pf[1], ones, accl[1], 0, 0, 0);
#pragma unroll
      for (int s = 0; s < 4; ++s) {
        const bf16x8 bv = *reinterpret_cast<const bf16x8*>(&bc[vofs + s * 1024]);
        O[0][s] = __builtin_amdgcn_mfma_f32_16x16x32_bf16(pf[0], bv, O[0][s], 0, 0, 0);
        O[1][s] = __builtin_amdgcn_mfma_f32_16x16x32_bf16(pf[1], bv, O[1][s], 0, 0, 0);
      }
    }
    __syncthreads();   // drains gll vmcnt -> next buffer valid; closes reads of bc
  }
#undef STAGE
  // ---- combine key-halves via Ob (bf16, stride 68, 128 rows) + lb (fp32) ----
  unsigned short* Ob = (unsigned short*)lds;            // [0, 8704) shorts
  float* lb = (float*)((unsigned short*)lds + 8704);    // 256 fp32 -> 9216 shorts
  if (wk == 1) {
#pragma unroll
    for (int u = 0; u < 2; ++u) {
#pragma unroll
      for (int s = 0; s < 4; ++s)
#pragma unroll
        for (int r = 0; r < 4; ++r)
          Ob[(wq * 32 + u * 16 + quad * 4 + r) * 68 + s * 16 + l16] = f2bits(O[u][s][r]);
      if (l16 == 0)
#pragma unroll
        for (int r = 0; r < 4; ++r)
          lb[128 + wq * 32 + u * 16 + quad * 4 + r] = accl[u][r];
    }
  } else {
#pragma unroll
    for (int u = 0; u < 2; ++u)
      if (l16 == 0)
#pragma unroll
        for (int r = 0; r < 4; ++r)
          lb[wq * 32 + u * 16 + quad * 4 + r] = accl[u][r];
  }
  __syncthreads();
  if (wk == 0) {
#pragma unroll
    for (int u = 0; u < 2; ++u)
#pragma unroll
      for (int r = 0; r < 4; ++r) {
        const int ql = wq * 32 + u * 16 + quad * 4 + r;
        const float linv = 1.f / (lb[ql] + lb[128 + ql]);
        const size_t orow = ((size_t)bi * NCTX + qrow0 + ql) * DIMD + hi * DH;
#pragma unroll
        for (int s = 0; s < 4; ++s)
          out[orow + s * 16 + l16] =
              f2bits((O[u][s][r] + bits2f(Ob[ql * 68 + s * 16 + l16])) * linv);
      }
  }
}

extern "C" void kernel_launch(void* const* d_in, const int* in_sizes, int n_in,
                              void* d_out, int out_size, void* d_ws, size_t ws_size,
                              hipStream_t stream) {
  const float* x     = (const float*)d_in[0];
  const float* pose  = (const float*)d_in[1];
  const float* gam   = (const float*)d_in[2];
  const float* bet   = (const float*)d_in[3];
  const float* wqkv  = (const float*)d_in[4];
  const float* wout  = (const float*)d_in[5];
  const float* betap = (const float*)d_in[6];
  float* out = (float*)d_out;

  unsigned short* xn    = (unsigned short*)d_ws;             // 8 MB (reused as aout)
  unsigned short* qkvb  = xn + (size_t)NROWS * DIMD;         // 24 MB
  unsigned short* wqkvT = qkvb + (size_t)NROWS * QKVN;       // 1.5 MB
  unsigned short* woutT = wqkvT + (size_t)QKVN * DIMD;       // 0.5 MB
  unsigned short* vtg   = woutT + (size_t)DIMD * DIMD;       // 8 MB  V^T (from ggemm1)
  float*          pbl   = (float*)(vtg + (size_t)NB * NH * DH * NCTX); // 32 KB
  unsigned short* aout  = xn;                                // alias: xn dead after GEMM1

  lntc_kernel<<<2048 + 384 + 4, 256, 0, stream>>>(
      x, gam, bet, xn, wqkv, wqkvT, wout, woutT, pose, betap, pbl);
  ggemm_kernel<unsigned short, true><<<dim3(QKVN / 128, NROWS / 128), 256, 0, stream>>>(
      xn, wqkvT, qkvb, vtg, NROWS, QKVN, DIMD);
  fattn_kernel<<<dim3(NCTX / 128, NH, NB), 512, 0, stream>>>(qkvb, vtg, pbl, aout);
  mgemm_kernel<float, false><<<dim3(DIMD / 128, NROWS / 128), 256, 0, stream>>>(
      aout, woutT, out, NROWS, DIMD, DIMD);
}